// Round 8
// baseline (619.789 us; speedup 1.0000x reference)
//
#include <hip/hip_runtime.h>
#include <cstdint>
#include <cstddef>

typedef _Float16 f16;
typedef _Float16 f16x2 __attribute__((ext_vector_type(2)));
typedef _Float16 f16x4 __attribute__((ext_vector_type(4)));
typedef _Float16 f16x8 __attribute__((ext_vector_type(8)));
typedef float f32x4 __attribute__((ext_vector_type(4)));

// ---------------------------------------------------------------------------
// async global->LDS, 16B per lane. LDS dest is WAVE-UNIFORM base; HW writes
// lane i at base + i*16 (m97/m104 semantics).
// ---------------------------------------------------------------------------
__device__ __forceinline__ void gl2lds16(const void* g, void* l) {
  __builtin_amdgcn_global_load_lds(
      (const __attribute__((address_space(1))) void*)(uintptr_t)g,
      (__attribute__((address_space(3))) void*)(uintptr_t)l,
      16, 0, 0);
}

// ---------------------------------------------------------------------------
// B-spline features for one x: out9 = [silu, B3_0..B3_7].
// Uniform pykan grid hardcoded: t_j = (j-3)*0.4 - 1.
// ---------------------------------------------------------------------------
__device__ __forceinline__ void kan_basis(float x, f16* out9) {
  float sig  = 1.0f / (1.0f + __expf(-x));
  out9[0] = (f16)(x * sig);

  float t[12];
#pragma unroll
  for (int j = 0; j < 12; ++j) t[j] = (float)(j - 3) * 0.4f - 1.0f;
  float b0[11];
#pragma unroll
  for (int j = 0; j < 11; ++j)
    b0[j] = (x >= t[j] && x < t[j + 1]) ? 1.0f : 0.0f;
  float b1[10];
#pragma unroll
  for (int j = 0; j < 10; ++j)
    b1[j] = (x - t[j]) * 2.5f * b0[j] + (t[j + 2] - x) * 2.5f * b0[j + 1];
  float b2[9];
#pragma unroll
  for (int j = 0; j < 9; ++j)
    b2[j] = (x - t[j]) * 1.25f * b1[j] + (t[j + 3] - x) * 1.25f * b1[j + 1];
#pragma unroll
  for (int j = 0; j < 8; ++j)
    out9[1 + j] = (f16)((x - t[j]) * (1.0f / 1.2f) * b2[j] +
                        (t[j + 4] - x) * (1.0f / 1.2f) * b2[j + 1]);
}

// ---------------------------------------------------------------------------
// MERGED prep+feat kernel (R7-verbatim; verified -45us).
// K-layout T-MAJOR: k = t*din + i.
// ---------------------------------------------------------------------------
__global__ __launch_bounds__(256) void kan_prep_feat(
    const float* __restrict__ coef, const float* __restrict__ sb,
    const float* __restrict__ ss, f16* __restrict__ Wt,
    const float* __restrict__ Xa, const float* __restrict__ Xb,
    f16* __restrict__ F,
    int dout, int din, int prepBlocks, int featB, int segW, int bShift)
{
  __shared__ float s_sb[32][32];   // [i][o]
  __shared__ float s_ss[32][32];
  __shared__ f16 s_w[32][288];     // [o][i*9+t]
  const int t = threadIdx.x;
  const int gid = blockIdx.x;
  const int K9 = 9 * din;

  if (gid < prepBlocks) {
    const int prepBX = dout >> 5;
    const int o0 = (gid % prepBX) * 32, i0 = (gid / prepBX) * 32;

    {
      int il = t >> 3, oc = (t & 7) * 4;
      float4 vb = *(const float4*)(sb + (size_t)(i0 + il) * dout + o0 + oc);
      float4 vs = *(const float4*)(ss + (size_t)(i0 + il) * dout + o0 + oc);
      s_sb[il][oc + 0] = vb.x; s_sb[il][oc + 1] = vb.y;
      s_sb[il][oc + 2] = vb.z; s_sb[il][oc + 3] = vb.w;
      s_ss[il][oc + 0] = vs.x; s_ss[il][oc + 1] = vs.y;
      s_ss[il][oc + 2] = vs.z; s_ss[il][oc + 3] = vs.w;
    }
    __syncthreads();

#pragma unroll
    for (int j = 0; j < 8; ++j) {
      int f  = j * 256 + t;
      int il = f >> 6, c = f & 63;
      int ol = c >> 1, gh = (c & 1) * 4;
      float4 v = *(const float4*)(coef + ((size_t)(i0 + il) * dout + (o0 + ol)) * 8 + gh);
      float ssv = s_ss[il][ol];
      f16* dst = &s_w[ol][il * 9 + 1 + gh];
      dst[0] = (f16)(v.x * ssv); dst[1] = (f16)(v.y * ssv);
      dst[2] = (f16)(v.z * ssv); dst[3] = (f16)(v.w * ssv);
    }
#pragma unroll
    for (int j = 0; j < 4; ++j) {
      int e = j * 256 + t; int il = e >> 5, ol = e & 31;
      s_w[ol][il * 9] = (f16)s_sb[il][ol];
    }
    __syncthreads();

    {  // t-major writeout: per (o,part), 9 planes x f16x4
      int o = t >> 3, part = t & 7;
      f16* dstRow = Wt + (size_t)(o0 + o) * K9 + i0 + part * 4;
#pragma unroll
      for (int tp = 0; tp < 9; ++tp) {
        f16x4 v;
#pragma unroll
        for (int j = 0; j < 4; ++j) v[j] = s_w[o][(part * 4 + j) * 9 + tp];
        *(f16x4*)(dstRow + (size_t)tp * din) = v;
      }
    }
    return;
  }

  // ---- feature branch ----
  int f   = gid - prepBlocks;
  int seg = (f >= featB) ? 1 : 0;
  int fi  = f - seg * featB;
  const float* X = seg ? Xb : Xa;
  const int halfW = segW >> 1;
  int idx2 = fi * 256 + t;
  int b  = idx2 >> bShift;
  int ii = idx2 & (halfW - 1);
  int i  = seg * segW + 2 * ii;

  float2 xv = *(const float2*)(X + (size_t)b * segW + 2 * ii);
  f16 s0[9], s1[9];
  kan_basis(xv.x, s0);
  kan_basis(xv.y, s1);

  f16* o = F + (size_t)b * K9 + i;
#pragma unroll
  for (int tp = 0; tp < 9; ++tp) {
    f16x2 v; v[0] = s0[tp]; v[1] = s1[tp];
    *(f16x2*)(o + (size_t)tp * din) = v;
  }
}

// ---------------------------------------------------------------------------
// GEMM: C[M,N] += A[M,K] * Bt[N,K]^T, fp16 in / fp32 out.
// R8: 128M x 256N block, BK=32, 4 waves (2x2), WAVE TILE 64x128, acc[4][8].
// Rationale: round time ~= a*(LDS bytes) + MFMA + const (R1-R6 series).
// 64x128 wave tiles cut LDS reads/FLOP and staged bytes/FLOP x0.75 vs 64x64,
// and halve A's HBM re-fetch (grid.x 8 -> 4), while KEEPING the only
// structure that works: 2 independent blocks/CU (ring-3 x 24KB = 72KB LDS),
// R0's issue-ahead pipeline and barrier pattern.
// Per step: 6 gl2lds/thread (A 2 + B 4). Ring-3, issue-ahead-2:
//   top of s: vmcnt(6) [drains step-s's 6; keeps s+1's 6]; barrier;
//   issue step s+2 into buf (s+2)%3 (= buf of s-1, readers done before
//   barrier-s); ds_read 4 af + 8 bf; 32 MFMA. Last step: vmcnt(0).
// XOR swizzle chunk^=((row>>1)&3) at source: verified 0 conflicts R0-R7.
// Grids sized 512 = exactly 2 resident/CU, no dispatch tail.
// ---------------------------------------------------------------------------
template <int SPLITK>
__global__ __launch_bounds__(256, 2) void kan_gemm(
    const f16* __restrict__ A, const f16* __restrict__ Bt,
    float* __restrict__ C, int N, int K)
{
  __shared__ __align__(16) f16 lds[3][12288];  // ring: [buf][ A:128x32 | B:256x32 ]
  const int tid   = threadIdx.x;
  const int lane  = tid & 63;
  const int w     = tid >> 6;
  const int waveM = w >> 1, waveN = w & 1;
  const int l16   = lane & 15, quad = lane >> 4;
  const size_t mBase = (size_t)blockIdx.y * 128;
  const size_t nBase = (size_t)blockIdx.x * 256;
  const int kChunk = K / SPLITK;
  const int k0     = blockIdx.z * kChunk;
  const int kSteps = kChunk >> 5;

  // A staging: 512 chunks of 16B (2/thread); B: 1024 chunks (4/thread).
  // chunk c -> row c>>2, pos c&3; source col-chunk = pos ^ ((row>>1)&3).
  const f16* gA[2]; int lA[2];
#pragma unroll
  for (int r = 0; r < 2; ++r) {
    int c = r * 256 + tid, row = c >> 2;
    int cs = (c & 3) ^ ((row >> 1) & 3);
    gA[r] = A + (mBase + row) * (size_t)K + k0 + cs * 8;
    lA[r] = (r * 256 + (tid & ~63)) * 8;
  }
  const f16* gB[4]; int lB[4];
#pragma unroll
  for (int r = 0; r < 4; ++r) {
    int c = r * 256 + tid, row = c >> 2;
    int cs = (c & 3) ^ ((row >> 1) & 3);
    gB[r] = Bt + (nBase + row) * (size_t)K + k0 + cs * 8;
    lB[r] = 4096 + (r * 256 + (tid & ~63)) * 8;
  }

  f32x4 acc[4][8] = {};

  // preload steps 0,1 into bufs 0,1 (kSteps >= 18 in all our shapes)
#pragma unroll
  for (int p = 0; p < 2; ++p) {
    f16* b = lds[p];
    int kk = p * 32;
    gl2lds16(gA[0] + kk, b + lA[0]);
    gl2lds16(gA[1] + kk, b + lA[1]);
#pragma unroll
    for (int r = 0; r < 4; ++r) gl2lds16(gB[r] + kk, b + lB[r]);
  }

  for (int s = 0; s < kSteps; ++s) {
    if (s < kSteps - 1) asm volatile("s_waitcnt vmcnt(6)" ::: "memory");
    else                asm volatile("s_waitcnt vmcnt(0)" ::: "memory");
    __builtin_amdgcn_s_barrier();

    if (s + 2 < kSteps) {  // refill the buffer freed by the barrier above
      int kk = (s + 2) * 32;
      f16* b = &lds[(s + 2) % 3][0];
      gl2lds16(gA[0] + kk, b + lA[0]);
      gl2lds16(gA[1] + kk, b + lA[1]);
#pragma unroll
      for (int r = 0; r < 4; ++r) gl2lds16(gB[r] + kk, b + lB[r]);
    }

    const f16* buf = &lds[s % 3][0];
    f16x8 af[4], bf[8];
#pragma unroll
    for (int mi = 0; mi < 4; ++mi) {
      int row = waveM * 64 + mi * 16 + l16;
      af[mi] = *(const f16x8*)(buf + row * 32 + (quad ^ ((row >> 1) & 3)) * 8);
    }
#pragma unroll
    for (int ni = 0; ni < 8; ++ni) {
      int col = waveN * 128 + ni * 16 + l16;
      bf[ni] = *(const f16x8*)(buf + 4096 + col * 32 + (quad ^ ((col >> 1) & 3)) * 8);
    }
#pragma unroll
    for (int mi = 0; mi < 4; ++mi)
#pragma unroll
      for (int ni = 0; ni < 8; ++ni)
        acc[mi][ni] = __builtin_amdgcn_mfma_f32_16x16x32_f16(
            af[mi], bf[ni], acc[mi][ni], 0, 0, 0);
  }

#pragma unroll
  for (int mi = 0; mi < 4; ++mi) {
    size_t row = mBase + waveM * 64 + mi * 16 + quad * 4;
#pragma unroll
    for (int ni = 0; ni < 8; ++ni) {
      size_t col = nBase + waveN * 128 + ni * 16 + l16;
#pragma unroll
      for (int r = 0; r < 4; ++r)
        unsafeAtomicAdd(C + (row + r) * N + col, acc[mi][ni][r]);
    }
  }
}

// ---------------------------------------------------------------------------
// Orchestration. WS: Wt (18.9MB) | F (75.5MB) | actA | actB (16.8MB each).
// 11 launches: 2 upfront memsets, 1 mid memset, 4 merged prep+feat, 4 GEMMs.
// GEMM grids = 512 blocks -> exactly 2 resident/CU, no dispatch tail.
// ---------------------------------------------------------------------------
extern "C" void kernel_launch(void* const* d_in, const int* in_sizes, int n_in,
                              void* d_out, int out_size, void* d_ws, size_t ws_size,
                              hipStream_t stream)
{
  const float* y = (const float*)d_in[0];
  const float* u = (const float*)d_in[1];
  const float* coef[4]; const float* sb[4]; const float* ss[4];
  for (int l = 0; l < 4; ++l) {
    coef[l] = (const float*)d_in[2 + 4 * l];
    sb[l]   = (const float*)d_in[3 + 4 * l];
    ss[l]   = (const float*)d_in[4 + 4 * l];
  }
  char* ws = (char*)d_ws;
  f16*   Wt   = (f16*)(ws);
  f16*   F    = (f16*)(ws + 18874368);                        // 9216*1024*2
  float* actA = (float*)(ws + 18874368 + 75497472);           // + 4096*9216*2
  float* actB = (float*)(ws + 18874368 + 75497472 + 16777216);
  float* out  = (float*)d_out;
  const size_t actBytes = (size_t)4096 * 1024 * 4;

  // upfront zeroing: actA|actB contiguous in one call; out separately.
  hipMemsetAsync(actA, 0, 2 * actBytes, stream);
  hipMemsetAsync(d_out, 0, (size_t)out_size * sizeof(float), stream);

  // Layer 0: in=512 (y|u), out=1024, K=4608. splitK=4 (kSteps 36).
  kan_prep_feat<<<512 + 4096, 256, 0, stream>>>(
      coef[0], sb[0], ss[0], Wt, y, u, F, 1024, 512, 512, 2048, 256, 7);
  kan_gemm<4><<<dim3(4, 32, 4), 256, 0, stream>>>(F, Wt, actA, 1024, 4608);

  // Layer 1: in=1024, out=1024, K=9216. splitK=4 (kSteps 72).
  kan_prep_feat<<<1024 + 8192, 256, 0, stream>>>(
      coef[1], sb[1], ss[1], Wt, actA, nullptr, F, 1024, 1024, 1024, 8192, 1024, 9);
  kan_gemm<4><<<dim3(4, 32, 4), 256, 0, stream>>>(F, Wt, actB, 1024, 9216);

  // re-zero actA (L2 output; actA last read by L1's feat above)
  hipMemsetAsync(actA, 0, actBytes, stream);

  // Layer 2: in=1024, out=1024, K=9216. splitK=4.
  kan_prep_feat<<<1024 + 8192, 256, 0, stream>>>(
      coef[2], sb[2], ss[2], Wt, actB, nullptr, F, 1024, 1024, 1024, 8192, 1024, 9);
  kan_gemm<4><<<dim3(4, 32, 4), 256, 0, stream>>>(F, Wt, actA, 1024, 9216);

  // Layer 3: in=1024, out=256, K=9216. splitK=16 (kSteps 18) -> 512 blocks.
  kan_prep_feat<<<256 + 8192, 256, 0, stream>>>(
      coef[3], sb[3], ss[3], Wt, actA, nullptr, F, 256, 1024, 256, 8192, 1024, 9);
  kan_gemm<16><<<dim3(1, 32, 16), 256, 0, stream>>>(F, Wt, out, 256, 9216);
}

// Round 10
// 553.459 us; speedup vs baseline: 1.1198x; 1.1198x over previous
//
#include <hip/hip_runtime.h>
#include <cstdint>
#include <cstddef>

typedef _Float16 f16;
typedef _Float16 f16x2 __attribute__((ext_vector_type(2)));
typedef _Float16 f16x4 __attribute__((ext_vector_type(4)));
typedef _Float16 f16x8 __attribute__((ext_vector_type(8)));
typedef float f32x4 __attribute__((ext_vector_type(4)));

// ---------------------------------------------------------------------------
// async global->LDS, 16B per lane. LDS dest is WAVE-UNIFORM base; HW writes
// lane i at base + i*16 (m97/m104 semantics).
// ---------------------------------------------------------------------------
__device__ __forceinline__ void gl2lds16(const void* g, void* l) {
  __builtin_amdgcn_global_load_lds(
      (const __attribute__((address_space(1))) void*)(uintptr_t)g,
      (__attribute__((address_space(3))) void*)(uintptr_t)l,
      16, 0, 0);
}

// ---------------------------------------------------------------------------
// B-spline features for one x: out9 = [silu, B3_0..B3_7].
// Uniform pykan grid hardcoded: t_j = (j-3)*0.4 - 1.
// ---------------------------------------------------------------------------
__device__ __forceinline__ void kan_basis(float x, f16* out9) {
  float sig  = 1.0f / (1.0f + __expf(-x));
  out9[0] = (f16)(x * sig);

  float t[12];
#pragma unroll
  for (int j = 0; j < 12; ++j) t[j] = (float)(j - 3) * 0.4f - 1.0f;
  float b0[11];
#pragma unroll
  for (int j = 0; j < 11; ++j)
    b0[j] = (x >= t[j] && x < t[j + 1]) ? 1.0f : 0.0f;
  float b1[10];
#pragma unroll
  for (int j = 0; j < 10; ++j)
    b1[j] = (x - t[j]) * 2.5f * b0[j] + (t[j + 2] - x) * 2.5f * b0[j + 1];
  float b2[9];
#pragma unroll
  for (int j = 0; j < 9; ++j)
    b2[j] = (x - t[j]) * 1.25f * b1[j] + (t[j + 3] - x) * 1.25f * b1[j + 1];
#pragma unroll
  for (int j = 0; j < 8; ++j)
    out9[1 + j] = (f16)((x - t[j]) * (1.0f / 1.2f) * b2[j] +
                        (t[j + 4] - x) * (1.0f / 1.2f) * b2[j + 1]);
}

// ---------------------------------------------------------------------------
// MERGED prep+feat kernel (R7-verbatim; verified -45us).
// K-layout T-MAJOR: k = t*din + i.
// ---------------------------------------------------------------------------
__global__ __launch_bounds__(256) void kan_prep_feat(
    const float* __restrict__ coef, const float* __restrict__ sb,
    const float* __restrict__ ss, f16* __restrict__ Wt,
    const float* __restrict__ Xa, const float* __restrict__ Xb,
    f16* __restrict__ F,
    int dout, int din, int prepBlocks, int featB, int segW, int bShift)
{
  __shared__ float s_sb[32][32];   // [i][o]
  __shared__ float s_ss[32][32];
  __shared__ f16 s_w[32][288];     // [o][i*9+t]
  const int t = threadIdx.x;
  const int gid = blockIdx.x;
  const int K9 = 9 * din;

  if (gid < prepBlocks) {
    const int prepBX = dout >> 5;
    const int o0 = (gid % prepBX) * 32, i0 = (gid / prepBX) * 32;

    {
      int il = t >> 3, oc = (t & 7) * 4;
      float4 vb = *(const float4*)(sb + (size_t)(i0 + il) * dout + o0 + oc);
      float4 vs = *(const float4*)(ss + (size_t)(i0 + il) * dout + o0 + oc);
      s_sb[il][oc + 0] = vb.x; s_sb[il][oc + 1] = vb.y;
      s_sb[il][oc + 2] = vb.z; s_sb[il][oc + 3] = vb.w;
      s_ss[il][oc + 0] = vs.x; s_ss[il][oc + 1] = vs.y;
      s_ss[il][oc + 2] = vs.z; s_ss[il][oc + 3] = vs.w;
    }
    __syncthreads();

#pragma unroll
    for (int j = 0; j < 8; ++j) {
      int f  = j * 256 + t;
      int il = f >> 6, c = f & 63;
      int ol = c >> 1, gh = (c & 1) * 4;
      float4 v = *(const float4*)(coef + ((size_t)(i0 + il) * dout + (o0 + ol)) * 8 + gh);
      float ssv = s_ss[il][ol];
      f16* dst = &s_w[ol][il * 9 + 1 + gh];
      dst[0] = (f16)(v.x * ssv); dst[1] = (f16)(v.y * ssv);
      dst[2] = (f16)(v.z * ssv); dst[3] = (f16)(v.w * ssv);
    }
#pragma unroll
    for (int j = 0; j < 4; ++j) {
      int e = j * 256 + t; int il = e >> 5, ol = e & 31;
      s_w[ol][il * 9] = (f16)s_sb[il][ol];
    }
    __syncthreads();

    {  // t-major writeout: per (o,part), 9 planes x f16x4
      int o = t >> 3, part = t & 7;
      f16* dstRow = Wt + (size_t)(o0 + o) * K9 + i0 + part * 4;
#pragma unroll
      for (int tp = 0; tp < 9; ++tp) {
        f16x4 v;
#pragma unroll
        for (int j = 0; j < 4; ++j) v[j] = s_w[o][(part * 4 + j) * 9 + tp];
        *(f16x4*)(dstRow + (size_t)tp * din) = v;
      }
    }
    return;
  }

  // ---- feature branch ----
  int f   = gid - prepBlocks;
  int seg = (f >= featB) ? 1 : 0;
  int fi  = f - seg * featB;
  const float* X = seg ? Xb : Xa;
  const int halfW = segW >> 1;
  int idx2 = fi * 256 + t;
  int b  = idx2 >> bShift;
  int ii = idx2 & (halfW - 1);
  int i  = seg * segW + 2 * ii;

  float2 xv = *(const float2*)(X + (size_t)b * segW + 2 * ii);
  f16 s0[9], s1[9];
  kan_basis(xv.x, s0);
  kan_basis(xv.y, s1);

  f16* o = F + (size_t)b * K9 + i;
#pragma unroll
  for (int tp = 0; tp < 9; ++tp) {
    f16x2 v; v[0] = s0[tp]; v[1] = s1[tp];
    *(f16x2*)(o + (size_t)tp * din) = v;
  }
}

// ---------------------------------------------------------------------------
// GEMM: C[M,N] += A[M,K] * Bt[N,K]^T, fp16 in / fp32 out.
// R9: R0 structure with TWO K-SLOTS PER BARRIER WINDOW.
// Series invariant (R0-R8): ~16 cy/MFMA regardless of tile, ring depth,
// blocks/CU, schedule, or LDS bytes/FLOP. Remaining unfalsified term: fixed
// per-barrier-window cost (all-wave rendezvous + drain + pipe re-ramp).
// This round halves barriers and vmcnt waits per FLOP with ZERO other change:
//   - same 128x128 tile, BK=32 slots, 16KB/slot, ring-4 = 64KB, 2 blocks/CU
//   - same XOR swizzle chunk^=((row>>1)&3) (0 conflicts R0-R8), same epilogue
//   - window w: vmcnt(0); barrier; stage slots 2w+2,2w+3 into the OTHER buf
//     pair (pair (w+1)&1, whose readers finished before barrier w); ds_read +
//     16 MFMA for slot 2w, then slot 2w+1 (pair w&1).
//   Loads issued at window w are drained at window w+1's top -> ~1 full
//   window (>3000cy) of cover >> 900cy HBM latency.
// kSteps even for all shapes (72/144/144/36).
// ---------------------------------------------------------------------------
template <int SPLITK>
__global__ __launch_bounds__(256, 2) void kan_gemm(
    const f16* __restrict__ A, const f16* __restrict__ Bt,
    float* __restrict__ C, int N, int K)
{
  __shared__ __align__(16) f16 lds[4][8192];  // 2 pairs x 2 slots x 16KB
  const int tid   = threadIdx.x;
  const int lane  = tid & 63;
  const int w     = tid >> 6;
  const int waveM = w >> 1, waveN = w & 1;
  const int l16   = lane & 15, quad = lane >> 4;
  const size_t mBase = (size_t)blockIdx.y * 128;
  const size_t nBase = (size_t)blockIdx.x * 128;
  const int kChunk = K / SPLITK;
  const int k0     = blockIdx.z * kChunk;
  const int kSteps = kChunk >> 5;   // even (36..144)

  // staging: A = 512 chunks of 16B (2/thread), B same. Swizzled at source.
  const f16* gA[2]; int lA[2];
  const f16* gB[2]; int lB[2];
#pragma unroll
  for (int r = 0; r < 2; ++r) {
    int g = r * 256 + tid, row = g >> 2;
    int cs = (g & 3) ^ ((row >> 1) & 3);
    gA[r] = A + (mBase + row) * (size_t)K + k0 + cs * 8;
    gB[r] = Bt + (nBase + row) * (size_t)K + k0 + cs * 8;
    lA[r] = (r * 256 + (tid & ~63)) * 8;
    lB[r] = 4096 + lA[r];
  }

  // fragment read offsets (f16 units, within a slot)
  int aOff[4], bOff[4];
#pragma unroll
  for (int mi = 0; mi < 4; ++mi) {
    int row = waveM * 64 + mi * 16 + l16;
    aOff[mi] = row * 32 + (quad ^ ((row >> 1) & 3)) * 8;
    int col = waveN * 64 + mi * 16 + l16;
    bOff[mi] = 4096 + col * 32 + (quad ^ ((col >> 1) & 3)) * 8;
  }

  f32x4 acc[4][4] = {};

  // prologue: stage slots 0,1 into bufs 0,1 (pair 0)
#pragma unroll
  for (int p = 0; p < 2; ++p) {
    f16* b = lds[p];
    int kk = p * 32;
#pragma unroll
    for (int r = 0; r < 2; ++r) {
      gl2lds16(gA[r] + kk, b + lA[r]);
      gl2lds16(gB[r] + kk, b + lB[r]);
    }
  }

  const int nw = kSteps >> 1;
  for (int wd = 0; wd < nw; ++wd) {
    asm volatile("s_waitcnt vmcnt(0)" ::: "memory");  // this pair's loads in
    __builtin_amdgcn_s_barrier();

    const int sp = (wd & 1) * 2;          // buf pair to read this window
    if (2 * wd + 2 < kSteps) {            // stage next pair (readers done w-1)
      const int spN = ((wd + 1) & 1) * 2;
#pragma unroll
      for (int q = 0; q < 2; ++q) {
        f16* b = lds[spN + q];
        int kk = (2 * wd + 2 + q) * 32;
#pragma unroll
        for (int r = 0; r < 2; ++r) {
          gl2lds16(gA[r] + kk, b + lA[r]);
          gl2lds16(gB[r] + kk, b + lB[r]);
        }
      }
    }

#pragma unroll
    for (int q = 0; q < 2; ++q) {
      const f16* buf = lds[sp + q];
      f16x8 af[4], bf[4];
#pragma unroll
      for (int mi = 0; mi < 4; ++mi) af[mi] = *(const f16x8*)(buf + aOff[mi]);
#pragma unroll
      for (int ni = 0; ni < 4; ++ni) bf[ni] = *(const f16x8*)(buf + bOff[ni]);
#pragma unroll
      for (int mi = 0; mi < 4; ++mi)
#pragma unroll
        for (int ni = 0; ni < 4; ++ni)
          acc[mi][ni] = __builtin_amdgcn_mfma_f32_16x16x32_f16(
              af[mi], bf[ni], acc[mi][ni], 0, 0, 0);
    }
  }

#pragma unroll
  for (int mi = 0; mi < 4; ++mi) {
    size_t row = mBase + waveM * 64 + mi * 16 + quad * 4;
#pragma unroll
    for (int ni = 0; ni < 4; ++ni) {
      size_t col = nBase + waveN * 64 + ni * 16 + l16;
#pragma unroll
      for (int r = 0; r < 4; ++r)
        unsafeAtomicAdd(C + (row + r) * N + col, acc[mi][ni][r]);
    }
  }
}

// ---------------------------------------------------------------------------
// Orchestration. WS: Wt (18.9MB) | F (75.5MB) | actA | actB [| actC].
// If ws_size allows a 3rd act buffer, skip the mid re-zero of actA (one
// dispatch + 16.8MB write saved); fallback = R7's re-zero path.
// GEMM grids = 512 blocks -> exactly 2 resident/CU, no dispatch tail.
// ---------------------------------------------------------------------------
extern "C" void kernel_launch(void* const* d_in, const int* in_sizes, int n_in,
                              void* d_out, int out_size, void* d_ws, size_t ws_size,
                              hipStream_t stream)
{
  const float* y = (const float*)d_in[0];
  const float* u = (const float*)d_in[1];
  const float* coef[4]; const float* sb[4]; const float* ss[4];
  for (int l = 0; l < 4; ++l) {
    coef[l] = (const float*)d_in[2 + 4 * l];
    sb[l]   = (const float*)d_in[3 + 4 * l];
    ss[l]   = (const float*)d_in[4 + 4 * l];
  }
  char* ws = (char*)d_ws;
  f16*   Wt   = (f16*)(ws);
  f16*   F    = (f16*)(ws + 18874368);                        // 9216*1024*2
  float* actA = (float*)(ws + 18874368 + 75497472);           // + 4096*9216*2
  float* actB = (float*)(ws + 18874368 + 75497472 + 16777216);
  float* out  = (float*)d_out;
  const size_t actBytes = (size_t)4096 * 1024 * 4;
  const size_t need3 = 18874368 + 75497472 + 3 * actBytes;
  const bool  three  = (ws_size >= need3);
  float* actC = three ? (float*)((char*)actB + actBytes) : actA;

  // upfront zeroing: act buffers contiguous in one call; out separately.
  hipMemsetAsync(actA, 0, (three ? 3 : 2) * actBytes, stream);
  hipMemsetAsync(d_out, 0, (size_t)out_size * sizeof(float), stream);

  // Layer 0: in=512 (y|u), out=1024, K=4608. splitK=2 (kSteps 72, 36 win).
  kan_prep_feat<<<512 + 4096, 256, 0, stream>>>(
      coef[0], sb[0], ss[0], Wt, y, u, F, 1024, 512, 512, 2048, 256, 7);
  kan_gemm<2><<<dim3(8, 32, 2), 256, 0, stream>>>(F, Wt, actA, 1024, 4608);

  // Layer 1: in=1024, out=1024, K=9216. splitK=2 (kSteps 144, 72 win).
  kan_prep_feat<<<1024 + 8192, 256, 0, stream>>>(
      coef[1], sb[1], ss[1], Wt, actA, nullptr, F, 1024, 1024, 1024, 8192, 1024, 9);
  kan_gemm<2><<<dim3(8, 32, 2), 256, 0, stream>>>(F, Wt, actB, 1024, 9216);

  if (!three) hipMemsetAsync(actA, 0, actBytes, stream);  // fallback re-zero

  // Layer 2: in=1024, out=1024, K=9216. splitK=2.
  kan_prep_feat<<<1024 + 8192, 256, 0, stream>>>(
      coef[2], sb[2], ss[2], Wt, actB, nullptr, F, 1024, 1024, 1024, 8192, 1024, 9);
  kan_gemm<2><<<dim3(8, 32, 2), 256, 0, stream>>>(F, Wt, actC, 1024, 9216);

  // Layer 3: in=1024, out=256, K=9216. splitK=8 (kSteps 36, 18 win).
  kan_prep_feat<<<256 + 8192, 256, 0, stream>>>(
      coef[3], sb[3], ss[3], Wt, actC, nullptr, F, 256, 1024, 256, 8192, 1024, 9);
  kan_gemm<8><<<dim3(2, 32, 8), 256, 0, stream>>>(F, Wt, out, 256, 9216);
}